// Round 7
// baseline (1593.025 us; speedup 1.0000x reference)
//
#include <hip/hip_runtime.h>

#define E_CNT 32768
#define V_CNT 98304
#define D_ 128
#define VOCAB_ 2000
#define ITERS_ 6

typedef unsigned short u16;
typedef _Float16 f16;
typedef __attribute__((ext_vector_type(8))) _Float16 f16x8;
typedef __attribute__((ext_vector_type(4))) float f32x4;

__device__ __forceinline__ f32x4 MFh(f16x8 a, f16x8 b, f32x4 c) {
    return __builtin_amdgcn_mfma_f32_16x16x32_f16(a, b, c, 0, 0, 0);
}
__device__ __forceinline__ float sigmoid_f(float x) { return 1.0f / (1.0f + __expf(-x)); }
__device__ __forceinline__ float tanh_f(float x) {
    float ax = fabsf(x);
    float t = 1.0f - 2.0f / (__expf(2.0f * ax) + 1.0f);
    return copysignf(t, x);
}

// LDS swizzles (element-unit). h tiles: XOR (row&15)<<3 halfs (16B slots) -> the 16
// rows a wave's ds_read_b128 spans land in 16 DISTINCT slots (verified: conflicts 0).
// CV (f32 scalar): XOR (row&15)<<2 words.
__device__ __forceinline__ int swzHV(int row, int col) { return (row * 384 + col) ^ ((row & 15) << 3); }
__device__ __forceinline__ int swzHE(int row, int col) { return (row * 128 + col) ^ ((row & 15) << 3); }
__device__ __forceinline__ int cvI(int row, int q)     { return row * 384 + (q ^ ((row & 15) << 2)); }

__global__ void detect_mask_kernel(const unsigned int* __restrict__ m, int* __restrict__ flag) {
    int i = blockIdx.x * 256 + threadIdx.x;
    if (i < 4096 && m[i] > 1u) atomicOr(flag, 1);
}

// Pack weights into MFMA B-fragment order.
// WvF (fp16): [nt(32)][kk(16)][lane(64)][8]  j = nt*16+(l&15), k = kk*32+(l>>4)*8+r
// WeF (fp16): [p(3)][nt(32)][kk(8)][64][8]
// OwF (fp16 hi/lo): [nt(125)][kk(4)][64][8]
__global__ void prep_kernel(
    const float* __restrict__ Wih_v2e, const float* __restrict__ Whh_v2e,
    const float* __restrict__ bih_v2e, const float* __restrict__ bhh_v2e,
    const float* __restrict__ Wih_e2v, const float* __restrict__ Whh_e2v,
    const float* __restrict__ bih_e2v, const float* __restrict__ bhh_e2v,
    const float* __restrict__ out_w,
    f16* __restrict__ WvF, f16* __restrict__ WeF,
    f16* __restrict__ OwFh, f16* __restrict__ OwFl,
    float* __restrict__ bv, float* __restrict__ be)
{
    int idx = blockIdx.x * 256 + threadIdx.x;
    if (idx < 262144) {
        const int r = idx & 7, l = (idx >> 3) & 63, t = idx >> 9;
        const int kk = t & 15, nt = t >> 4;
        const int j = nt * 16 + (l & 15);
        const int k = kk * 32 + (l >> 4) * 8 + r;
        const float w = (k < 384) ? Wih_v2e[j * 384 + k] : Whh_v2e[j * 128 + (k - 384)];
        WvF[idx] = (f16)w;
        return;
    }
    idx -= 262144;
    if (idx < 393216) {
        const int r = idx & 7, l = (idx >> 3) & 63, t = idx >> 9;  // t < 768
        const int kk = t & 7, nt = (t >> 3) & 31, p = t >> 8;
        const int j = nt * 16 + (l & 15);
        const int k = kk * 32 + (l >> 4) * 8 + r;
        const float w = (k < 128) ? Wih_e2v[(p * 512 + j) * 128 + k]
                                  : Whh_e2v[(p * 512 + j) * 128 + (k - 128)];
        WeF[idx] = (f16)w;
        return;
    }
    idx -= 393216;
    if (idx < 256000) {
        const int r = idx & 7, l = (idx >> 3) & 63, t = idx >> 9;  // t < 500
        const int kk = t & 3, nt = t >> 2;
        const int j = nt * 16 + (l & 15);
        const int k = kk * 32 + (l >> 4) * 8 + r;
        const float w = out_w[j * 128 + k];
        const f16 h = (f16)w;
        OwFh[idx] = h;
        OwFl[idx] = (f16)(w - (float)h);
        return;
    }
    idx -= 256000;
    if (idx < 512) { bv[idx] = bih_v2e[idx] + bhh_v2e[idx]; return; }
    idx -= 512;
    if (idx < 1536) { be[idx] = bih_e2v[idx] + bhh_e2v[idx]; return; }
}

// Persistent fused kernel: block = 1024 threads (16 waves) owns 64 edges for all 6 iters.
// Wave (c, wm) = (wid&7, wid>>3): gate-dim slice d = c*16+lr, edge rows [wm*32, wm*32+32).
// __launch_bounds__(1024, 4): min 4 waves/EU -> VGPR cap 512/4 = 128 >= live set ~95.
// (Round 6 bug: bare launch_bounds(1024) let the allocator pick 64 VGPRs -> 1.4 GB
// scratch spill traffic. The 2nd arg is the only reliable budget pin.)
// LDS (160 KB exact): HV fp16 [64][384] 48K + HE fp16 [64][128] 16K + CV f32 [64][384] 96K.
__global__ __launch_bounds__(1024, 4)
void fused_kernel(
    const int* __restrict__ x_v,
    const float* __restrict__ emb,
    const float* __restrict__ eiw, const float* __restrict__ eib,
    const f16* __restrict__ WvF, const f16* __restrict__ WeF,
    const float* __restrict__ bv, const float* __restrict__ be,
    const void* __restrict__ mask, const int* __restrict__ flagp,
    f16* __restrict__ hvOut)
{
    extern __shared__ char lds[];
    f16*   HV = (f16*)lds;                 // 24576 halfs
    f16*   HE = (f16*)(lds + 49152);       // 8192 halfs
    float* CV = (float*)(lds + 65536);     // 24576 floats

    const int tid = threadIdx.x;
    const int wid = tid >> 6, l = tid & 63;
    const int c = wid & 7, wm = wid >> 3;
    const int lr = l & 15, lk = l >> 4;
    const int e0 = blockIdx.x * 64;
    const int rbase = wm * 32;

    // ---- init h_v from embeddings (fp16 into LDS)
    for (int i = tid; i < 64 * 48; i += 1024) {
        const int row = i / 48, seg = i % 48;
        const int col0 = seg * 8;
        int id = x_v[(e0 + row) * 3 + (col0 >> 7)];
        if (id < 0 || id > VOCAB_) id = VOCAB_;
        const float* s = emb + id * D_ + (col0 & 127);
        float4 a = *(const float4*)s, b = *(const float4*)(s + 4);
        f16x8 H;
        H[0] = (f16)a.x; H[1] = (f16)a.y; H[2] = (f16)a.z; H[3] = (f16)a.w;
        H[4] = (f16)b.x; H[5] = (f16)b.y; H[6] = (f16)b.z; H[7] = (f16)b.w;
        *(f16x8*)&HV[swzHV(row, col0)] = H;
    }
    // ---- init h_e (same vector for every edge) and CV = 0
    for (int i = tid; i < 64 * 16; i += 1024) {
        const int row = i / 16, col0 = (i % 16) * 8;
        f16x8 H;
        #pragma unroll
        for (int j = 0; j < 8; ++j) H[j] = (f16)(eiw[col0 + j] + eib[col0 + j]);
        *(f16x8*)&HE[swzHE(row, col0)] = H;
    }
    for (int i = tid; i < 24576; i += 1024) CV[i] = 0.0f;   // swizzle is per-row bijection

    // ---- per-lane constants: mask bits, c_e state
    const int isByte = *flagp;
    unsigned mbits[3];
    #pragma unroll
    for (int p = 0; p < 3; ++p) {
        unsigned mb = 0;
        #pragma unroll
        for (int mt = 0; mt < 2; ++mt)
            #pragma unroll
            for (int r = 0; r < 4; ++r) {
                const int v = (e0 + rbase + mt * 16 + lk * 4 + r) * 3 + p;
                const bool m = isByte ? (((const unsigned char*)mask)[v] != 0)
                                      : (((const int*)mask)[v] != 0);
                mb |= (unsigned)m << (mt * 4 + r);
            }
        mbits[p] = mb;
    }
    const int d = c * 16 + lr;
    float ce[2][4];
    #pragma unroll
    for (int mt = 0; mt < 2; ++mt)
        #pragma unroll
        for (int r = 0; r < 4; ++r) ce[mt][r] = 0.0f;

    __syncthreads();

#define GEMM_STEP(WF, FBASE)                                                  \
    { _Pragma("unroll")                                                       \
      for (int g = 0; g < 4; ++g) {                                           \
          f16x8 B = *(const f16x8*)((WF) + (FBASE));                          \
          _Pragma("unroll")                                                   \
          for (int mt = 0; mt < 2; ++mt) acc[mt][g] = MFh(Ah[mt], B, acc[mt][g]); \
      } }

    #pragma unroll 1
    for (int it = 0; it < ITERS_; ++it) {
        // ======== vertex -> edge ========
        {
            f32x4 acc[2][4];
            #pragma unroll
            for (int mt = 0; mt < 2; ++mt)
                #pragma unroll
                for (int g = 0; g < 4; ++g) acc[mt][g] = (f32x4)0.0f;

            #pragma unroll 2
            for (int kk = 0; kk < 12; ++kk) {
                f16x8 Ah[2];
                #pragma unroll
                for (int mt = 0; mt < 2; ++mt)
                    Ah[mt] = *(const f16x8*)&HV[swzHV(rbase + mt * 16 + lr, kk * 32 + lk * 8)];
                GEMM_STEP(WvF, (((g * 8 + c) * 16 + kk) * 64 + l) * 8)
            }
            #pragma unroll 2
            for (int kk = 12; kk < 16; ++kk) {
                f16x8 Ah[2];
                #pragma unroll
                for (int mt = 0; mt < 2; ++mt)
                    Ah[mt] = *(const f16x8*)&HE[swzHE(rbase + mt * 16 + lr, (kk - 12) * 32 + lk * 8)];
                GEMM_STEP(WvF, (((g * 8 + c) * 16 + kk) * 64 + l) * 8)
            }
            __syncthreads();   // all HE reads done before HE writes
            const float bvi = bv[d], bvf = bv[128 + d], bvg = bv[256 + d], bvo = bv[384 + d];
            #pragma unroll
            for (int mt = 0; mt < 2; ++mt)
                #pragma unroll
                for (int r = 0; r < 4; ++r) {
                    const int row = rbase + mt * 16 + lk * 4 + r;
                    float gi = sigmoid_f(acc[mt][0][r] + bvi);
                    float gf = sigmoid_f(acc[mt][1][r] + bvf);
                    float gg = tanh_f(acc[mt][2][r] + bvg);
                    float go = sigmoid_f(acc[mt][3][r] + bvo);
                    float cn = gf * ce[mt][r] + gi * gg;
                    ce[mt][r] = cn;
                    HE[swzHE(row, d)] = (f16)(go * tanh_f(cn));
                }
            __syncthreads();   // HE complete before e2v reads
        }
        // ======== edge -> vertex (3 position-specific LSTMs) ========
        #pragma unroll
        for (int p = 0; p < 3; ++p) {
            f32x4 acc[2][4];
            #pragma unroll
            for (int mt = 0; mt < 2; ++mt)
                #pragma unroll
                for (int g = 0; g < 4; ++g) acc[mt][g] = (f32x4)0.0f;

            #pragma unroll 2
            for (int kk = 0; kk < 4; ++kk) {
                f16x8 Ah[2];
                #pragma unroll
                for (int mt = 0; mt < 2; ++mt)
                    Ah[mt] = *(const f16x8*)&HE[swzHE(rbase + mt * 16 + lr, kk * 32 + lk * 8)];
                GEMM_STEP(WeF, ((((p * 32) + (g * 8 + c)) * 8 + kk) * 64 + l) * 8)
            }
            #pragma unroll 2
            for (int kk = 4; kk < 8; ++kk) {
                f16x8 Ah[2];
                #pragma unroll
                for (int mt = 0; mt < 2; ++mt)
                    Ah[mt] = *(const f16x8*)&HV[swzHV(rbase + mt * 16 + lr, p * 128 + (kk - 4) * 32 + lk * 8)];
                GEMM_STEP(WeF, ((((p * 32) + (g * 8 + c)) * 8 + kk) * 64 + l) * 8)
            }
            __syncthreads();   // all HV[p]/HE reads done before HV[p] writes
            const float bei = be[p * 512 + d], bef = be[p * 512 + 128 + d];
            const float beg = be[p * 512 + 256 + d], beo = be[p * 512 + 384 + d];
            #pragma unroll
            for (int mt = 0; mt < 2; ++mt)
                #pragma unroll
                for (int r = 0; r < 4; ++r) {
                    if ((mbits[p] >> (mt * 4 + r)) & 1u) {
                        const int row = rbase + mt * 16 + lk * 4 + r;
                        float gi = sigmoid_f(acc[mt][0][r] + bei);
                        float gf = sigmoid_f(acc[mt][1][r] + bef);
                        float gg = tanh_f(acc[mt][2][r] + beg);
                        float go = sigmoid_f(acc[mt][3][r] + beo);
                        const int ci = cvI(row, p * 128 + d);
                        float cn = gf * CV[ci] + gi * gg;
                        CV[ci] = cn;
                        HV[swzHV(row, p * 128 + d)] = (f16)(go * tanh_f(cn));
                    }
                }
            // no barrier between cell(p) and GEMM(p+1): disjoint LDS regions
        }
        __syncthreads();       // HV writes complete before next v2e (or copy-out)
    }

    // ---- write final h_v (fp16) for the projection kernel: [vertex][128] row-major
    for (int i = tid; i < 64 * 48; i += 1024) {
        const int row = i / 48, col0 = (i % 48) * 8;
        *(f16x8*)&hvOut[(size_t)(e0 + row) * 384 + col0] = *(const f16x8*)&HV[swzHV(row, col0)];
    }
#undef GEMM_STEP
}

// logits = h_v @ out_w^T + out_b, computed with SWAPPED MFMA operands:
// D = A(out_w) * B(h_v)  ->  C row = vocab n (lane>>4)*4+reg, col = vertex (lane&15).
// Each lane holds 4 CONSECUTIVE vocab entries for one vertex -> float4 stores.
// Wave owns 64 vertices (16 persistent h_v B-frags, 64 VGPR); streams OwF hi then lo.
// 1536 waves total -> OwF re-read 1536 x 2 MB = 3 GB L2 (vs 6 GB before).
__global__ __launch_bounds__(256, 4) void proj_kernel(
    const f16* __restrict__ hv,
    const f16* __restrict__ WFh, const f16* __restrict__ WFl,
    const float* __restrict__ out_b, float* __restrict__ out)
{
    const int tid = threadIdx.x, l = tid & 63;
    const int wid = blockIdx.x * 4 + (tid >> 6);   // 0..1535
    const int v0 = wid * 64;
    const int lr = l & 15, lk = l >> 4;

    f16x8 Bv[4][4];                                // h_v fragments: 4 vertex-tiles x 4 kk
    #pragma unroll
    for (int vt = 0; vt < 4; ++vt)
        #pragma unroll
        for (int kk = 0; kk < 4; ++kk)
            Bv[vt][kk] = *(const f16x8*)(hv + (v0 + vt * 16 + lr) * D_ + kk * 32 + lk * 8);

    for (int nt = 0; nt < 125; ++nt) {
        f32x4 acc[4];
        #pragma unroll
        for (int vt = 0; vt < 4; ++vt) acc[vt] = (f32x4)0.0f;
        #pragma unroll
        for (int kk = 0; kk < 4; ++kk) {
            const f16x8 Ah = *(const f16x8*)(WFh + ((nt * 4 + kk) * 64 + l) * 8);
            #pragma unroll
            for (int vt = 0; vt < 4; ++vt) acc[vt] = MFh(Ah, Bv[vt][kk], acc[vt]);
        }
        #pragma unroll
        for (int kk = 0; kk < 4; ++kk) {
            const f16x8 Al = *(const f16x8*)(WFl + ((nt * 4 + kk) * 64 + l) * 8);
            #pragma unroll
            for (int vt = 0; vt < 4; ++vt) acc[vt] = MFh(Al, Bv[vt][kk], acc[vt]);
        }
        const int n0 = nt * 16 + lk * 4;
        const float4 bb = *(const float4*)&out_b[n0];
        #pragma unroll
        for (int vt = 0; vt < 4; ++vt) {
            const size_t v = (size_t)(v0 + vt * 16 + lr);
            float4 o = make_float4(acc[vt][0] + bb.x, acc[vt][1] + bb.y,
                                   acc[vt][2] + bb.z, acc[vt][3] + bb.w);
            *(float4*)&out[v * VOCAB_ + n0] = o;
        }
    }
}

extern "C" void kernel_launch(void* const* d_in, const int* in_sizes, int n_in,
                              void* d_out, int out_size, void* d_ws, size_t ws_size,
                              hipStream_t stream)
{
    const int*   x_v     = (const int*)  d_in[0];
    const void*  mask    = d_in[1];
    const float* emb     = (const float*)d_in[2];
    const float* eiw     = (const float*)d_in[3];
    const float* eib     = (const float*)d_in[4];
    const float* Wih_v2e = (const float*)d_in[5];
    const float* Whh_v2e = (const float*)d_in[6];
    const float* bih_v2e = (const float*)d_in[7];
    const float* bhh_v2e = (const float*)d_in[8];
    const float* Wih_e2v = (const float*)d_in[9];
    const float* Whh_e2v = (const float*)d_in[10];
    const float* bih_e2v = (const float*)d_in[11];
    const float* bhh_e2v = (const float*)d_in[12];
    const float* out_w   = (const float*)d_in[13];
    const float* out_b   = (const float*)d_in[14];
    float* out = (float*)d_out;

    // d_ws carve (~27.5 MB)
    char* ws = (char*)d_ws;
    f16*   hv   = (f16*)(ws);                  // 25165824 B
    f16*   WvF  = (f16*)(ws + 25165824);       // 524288
    f16*   WeF  = (f16*)(ws + 25690112);       // 786432
    f16*   OwFh = (f16*)(ws + 26476544);       // 512000
    f16*   OwFl = (f16*)(ws + 26988544);       // 512000
    float* bv   = (float*)(ws + 27500544);     // 2048
    float* be   = (float*)(ws + 27502592);     // 6144
    int*   flag = (int*)(ws + 27508736);

    hipFuncSetAttribute(reinterpret_cast<const void*>(fused_kernel),
                        hipFuncAttributeMaxDynamicSharedMemorySize, 163840);

    hipMemsetAsync(flag, 0, 4, stream);
    detect_mask_kernel<<<16, 256, 0, stream>>>((const unsigned int*)mask, flag);
    prep_kernel<<<3568, 256, 0, stream>>>(Wih_v2e, Whh_v2e, bih_v2e, bhh_v2e,
                                          Wih_e2v, Whh_e2v, bih_e2v, bhh_e2v, out_w,
                                          WvF, WeF, OwFh, OwFl, bv, be);
    fused_kernel<<<E_CNT / 64, 1024, 163840, stream>>>(x_v, emb, eiw, eib,
                                                       WvF, WeF, bv, be,
                                                       mask, flag, hv);
    proj_kernel<<<384, 256, 0, stream>>>(hv, OwFh, OwFl, out_b, out);
}

// Round 8
// 1013.072 us; speedup vs baseline: 1.5725x; 1.5725x over previous
//
#include <hip/hip_runtime.h>

#define E_CNT 32768
#define V_CNT 98304
#define D_ 128
#define VOCAB_ 2000
#define ITERS_ 6

typedef unsigned short u16;
typedef _Float16 f16;
typedef __attribute__((ext_vector_type(8))) _Float16 f16x8;
typedef __attribute__((ext_vector_type(4))) float f32x4;

__device__ __forceinline__ f32x4 MFh(f16x8 a, f16x8 b, f32x4 c) {
    return __builtin_amdgcn_mfma_f32_16x16x32_f16(a, b, c, 0, 0, 0);
}
__device__ __forceinline__ float sigmoid_f(float x) { return 1.0f / (1.0f + __expf(-x)); }
__device__ __forceinline__ float tanh_f(float x) {
    float ax = fabsf(x);
    float t = 1.0f - 2.0f / (__expf(2.0f * ax) + 1.0f);
    return copysignf(t, x);
}

// LDS swizzles (half-unit index). XOR (row&15)<<3 halfs (16B slots): the 16 rows a
// wave's ds_read_b128 spans land in 16 distinct slots (round-6 verified: conflicts 0).
// Bijective per row: row*384 (and *128) are multiples of 128 halfs, col<384, XOR only
// touches bits 3..6 of col-mod-128.
__device__ __forceinline__ int swzHV(int row, int col) { return (row * 384 + col) ^ ((row & 15) << 3); }
__device__ __forceinline__ int swzHE(int row, int col) { return (row * 128 + col) ^ ((row & 15) << 3); }

__global__ void detect_mask_kernel(const unsigned int* __restrict__ m, int* __restrict__ flag) {
    int i = blockIdx.x * 256 + threadIdx.x;
    if (i < 4096 && m[i] > 1u) atomicOr(flag, 1);
}

// Pack weights into MFMA B-fragment order.
// WvF (fp16): [nt(32)][kk(16)][lane(64)][8]  j = nt*16+(l&15), k = kk*32+(l>>4)*8+r
// WeF (fp16): [p(3)][nt(32)][kk(8)][64][8]
// OwF (fp16 hi/lo): [nt(125)][kk(4)][64][8]
__global__ void prep_kernel(
    const float* __restrict__ Wih_v2e, const float* __restrict__ Whh_v2e,
    const float* __restrict__ bih_v2e, const float* __restrict__ bhh_v2e,
    const float* __restrict__ Wih_e2v, const float* __restrict__ Whh_e2v,
    const float* __restrict__ bih_e2v, const float* __restrict__ bhh_e2v,
    const float* __restrict__ out_w,
    f16* __restrict__ WvF, f16* __restrict__ WeF,
    f16* __restrict__ OwFh, f16* __restrict__ OwFl,
    float* __restrict__ bv, float* __restrict__ be)
{
    int idx = blockIdx.x * 256 + threadIdx.x;
    if (idx < 262144) {
        const int r = idx & 7, l = (idx >> 3) & 63, t = idx >> 9;
        const int kk = t & 15, nt = t >> 4;
        const int j = nt * 16 + (l & 15);
        const int k = kk * 32 + (l >> 4) * 8 + r;
        const float w = (k < 384) ? Wih_v2e[j * 384 + k] : Whh_v2e[j * 128 + (k - 384)];
        WvF[idx] = (f16)w;
        return;
    }
    idx -= 262144;
    if (idx < 393216) {
        const int r = idx & 7, l = (idx >> 3) & 63, t = idx >> 9;  // t < 768
        const int kk = t & 7, nt = (t >> 3) & 31, p = t >> 8;
        const int j = nt * 16 + (l & 15);
        const int k = kk * 32 + (l >> 4) * 8 + r;
        const float w = (k < 128) ? Wih_e2v[(p * 512 + j) * 128 + k]
                                  : Whh_e2v[(p * 512 + j) * 128 + (k - 128)];
        WeF[idx] = (f16)w;
        return;
    }
    idx -= 393216;
    if (idx < 256000) {
        const int r = idx & 7, l = (idx >> 3) & 63, t = idx >> 9;  // t < 500
        const int kk = t & 3, nt = t >> 2;
        const int j = nt * 16 + (l & 15);
        const int k = kk * 32 + (l >> 4) * 8 + r;
        const float w = out_w[j * 128 + k];
        const f16 h = (f16)w;
        OwFh[idx] = h;
        OwFl[idx] = (f16)(w - (float)h);
        return;
    }
    idx -= 256000;
    if (idx < 512) { bv[idx] = bih_v2e[idx] + bhh_v2e[idx]; return; }
    idx -= 512;
    if (idx < 1536) { be[idx] = bih_e2v[idx] + bhh_e2v[idx]; return; }
}

// Persistent fused kernel: block = 512 threads (8 waves) owns 64 edges for all 6 iters.
// Wave c = wid (0..7): gate-dim slice d = c*16+lr for all 4 gates, edge tiles mt=0..3.
// STATIC __shared__ 64 KB (the whole point): compiler sees LDS -> occupancy model says
// 2 blocks/CU = 4 waves/EU -> VGPR budget 128 >= live set ~120 -> NO SPILLS.
// (Rounds 3-7 bug: dynamic LDS hid occupancy; allocator targeted 8 waves/EU = 64 VGPR
// and spilled ~1.4 GB/dispatch. launch_bounds 2nd arg couldn't stop it - it's a min.)
// c_v lives in GLOBAL f32 [E][3][128] (L3-resident, 50 MB); it==0 skips the load so no
// init pass; masked lanes never read or write their slot.
__global__ __launch_bounds__(512)
void fused_kernel(
    const int* __restrict__ x_v,
    const float* __restrict__ emb,
    const float* __restrict__ eiw, const float* __restrict__ eib,
    const f16* __restrict__ WvF, const f16* __restrict__ WeF,
    const float* __restrict__ bv, const float* __restrict__ be,
    const void* __restrict__ mask, const int* __restrict__ flagp,
    float* __restrict__ cvG,
    f16* __restrict__ hvOut)
{
    __shared__ f16 HV[24576];   // [64][384] swizzled, 48 KB
    __shared__ f16 HE[8192];    // [64][128] swizzled, 16 KB

    const int tid = threadIdx.x;
    const int c = tid >> 6, l = tid & 63;
    const int lr = l & 15, lk = l >> 4;
    const int e0 = blockIdx.x * 64;

    // ---- init h_v from embeddings (fp16 into LDS)
    for (int i = tid; i < 64 * 48; i += 512) {
        const int row = i / 48, seg = i % 48;
        const int col0 = seg * 8;
        int id = x_v[(e0 + row) * 3 + (col0 >> 7)];
        if (id < 0 || id > VOCAB_) id = VOCAB_;
        const float* s = emb + id * D_ + (col0 & 127);
        float4 a = *(const float4*)s, b = *(const float4*)(s + 4);
        f16x8 H;
        H[0] = (f16)a.x; H[1] = (f16)a.y; H[2] = (f16)a.z; H[3] = (f16)a.w;
        H[4] = (f16)b.x; H[5] = (f16)b.y; H[6] = (f16)b.z; H[7] = (f16)b.w;
        *(f16x8*)&HV[swzHV(row, col0)] = H;
    }
    // ---- init h_e (same vector for every edge)
    for (int i = tid; i < 64 * 16; i += 512) {
        const int row = i / 16, col0 = (i % 16) * 8;
        f16x8 H;
        #pragma unroll
        for (int j = 0; j < 8; ++j) H[j] = (f16)(eiw[col0 + j] + eib[col0 + j]);
        *(f16x8*)&HE[swzHE(row, col0)] = H;
    }

    // ---- per-lane constants: mask bits, c_e register state
    const int isByte = *flagp;
    unsigned mbits[3];
    #pragma unroll
    for (int p = 0; p < 3; ++p) {
        unsigned mb = 0;
        #pragma unroll
        for (int mt = 0; mt < 4; ++mt)
            #pragma unroll
            for (int r = 0; r < 4; ++r) {
                const int v = (e0 + mt * 16 + lk * 4 + r) * 3 + p;
                const bool m = isByte ? (((const unsigned char*)mask)[v] != 0)
                                      : (((const int*)mask)[v] != 0);
                mb |= (unsigned)m << (mt * 4 + r);
            }
        mbits[p] = mb;
    }
    const int d = c * 16 + lr;
    float ce[4][4];
    #pragma unroll
    for (int mt = 0; mt < 4; ++mt)
        #pragma unroll
        for (int r = 0; r < 4; ++r) ce[mt][r] = 0.0f;

    __syncthreads();

// g outer, mt inner: same-accumulator MFMA distance 4
#define GEMM_STEP(WF, FBASE)                                                  \
    { _Pragma("unroll")                                                       \
      for (int g = 0; g < 4; ++g) {                                           \
          f16x8 B = *(const f16x8*)((WF) + (FBASE));                          \
          _Pragma("unroll")                                                   \
          for (int mt = 0; mt < 4; ++mt) acc[mt][g] = MFh(Ah[mt], B, acc[mt][g]); \
      } }

    #pragma unroll 1
    for (int it = 0; it < ITERS_; ++it) {
        // ======== vertex -> edge ========
        {
            f32x4 acc[4][4];
            #pragma unroll
            for (int mt = 0; mt < 4; ++mt)
                #pragma unroll
                for (int g = 0; g < 4; ++g) acc[mt][g] = (f32x4)0.0f;

            #pragma unroll 1
            for (int kk = 0; kk < 12; ++kk) {
                f16x8 Ah[4];
                #pragma unroll
                for (int mt = 0; mt < 4; ++mt)
                    Ah[mt] = *(const f16x8*)&HV[swzHV(mt * 16 + lr, kk * 32 + lk * 8)];
                GEMM_STEP(WvF, (((g * 8 + c) * 16 + kk) * 64 + l) * 8)
            }
            #pragma unroll 1
            for (int kk = 12; kk < 16; ++kk) {
                f16x8 Ah[4];
                #pragma unroll
                for (int mt = 0; mt < 4; ++mt)
                    Ah[mt] = *(const f16x8*)&HE[swzHE(mt * 16 + lr, (kk - 12) * 32 + lk * 8)];
                GEMM_STEP(WvF, (((g * 8 + c) * 16 + kk) * 64 + l) * 8)
            }
            __syncthreads();   // all HE reads done before HE writes
            const float bvi = bv[d], bvf = bv[128 + d], bvg = bv[256 + d], bvo = bv[384 + d];
            #pragma unroll
            for (int mt = 0; mt < 4; ++mt)
                #pragma unroll
                for (int r = 0; r < 4; ++r) {
                    const int row = mt * 16 + lk * 4 + r;
                    float gi = sigmoid_f(acc[mt][0][r] + bvi);
                    float gf = sigmoid_f(acc[mt][1][r] + bvf);
                    float gg = tanh_f(acc[mt][2][r] + bvg);
                    float go = sigmoid_f(acc[mt][3][r] + bvo);
                    float cn = gf * ce[mt][r] + gi * gg;
                    ce[mt][r] = cn;
                    HE[swzHE(row, d)] = (f16)(go * tanh_f(cn));
                }
            __syncthreads();   // HE complete before e2v reads
        }
        // ======== edge -> vertex (3 position-specific LSTMs) ========
        #pragma unroll 1
        for (int p = 0; p < 3; ++p) {
            f32x4 acc[4][4];
            #pragma unroll
            for (int mt = 0; mt < 4; ++mt)
                #pragma unroll
                for (int g = 0; g < 4; ++g) acc[mt][g] = (f32x4)0.0f;

            #pragma unroll 1
            for (int kk = 0; kk < 4; ++kk) {
                f16x8 Ah[4];
                #pragma unroll
                for (int mt = 0; mt < 4; ++mt)
                    Ah[mt] = *(const f16x8*)&HE[swzHE(mt * 16 + lr, kk * 32 + lk * 8)];
                GEMM_STEP(WeF, ((((p * 32) + (g * 8 + c)) * 8 + kk) * 64 + l) * 8)
            }
            #pragma unroll 1
            for (int kk = 4; kk < 8; ++kk) {
                f16x8 Ah[4];
                #pragma unroll
                for (int mt = 0; mt < 4; ++mt)
                    Ah[mt] = *(const f16x8*)&HV[swzHV(mt * 16 + lr, p * 128 + (kk - 4) * 32 + lk * 8)];
                GEMM_STEP(WeF, ((((p * 32) + (g * 8 + c)) * 8 + kk) * 64 + l) * 8)
            }
            __syncthreads();   // all HV[p]/HE reads done before HV[p] writes
            const float bei = be[p * 512 + d], bef = be[p * 512 + 128 + d];
            const float beg = be[p * 512 + 256 + d], beo = be[p * 512 + 384 + d];
            #pragma unroll
            for (int mt = 0; mt < 4; ++mt)
                #pragma unroll
                for (int r = 0; r < 4; ++r) {
                    if ((mbits[p] >> (mt * 4 + r)) & 1u) {
                        const int row = mt * 16 + lk * 4 + r;
                        float gi = sigmoid_f(acc[mt][0][r] + bei);
                        float gf = sigmoid_f(acc[mt][1][r] + bef);
                        float gg = tanh_f(acc[mt][2][r] + beg);
                        float go = sigmoid_f(acc[mt][3][r] + beo);
                        const size_t co = ((size_t)(e0 + row) * 3 + p) * 128 + d;
                        float cvold = (it == 0) ? 0.0f : cvG[co];
                        float cn = gf * cvold + gi * gg;
                        cvG[co] = cn;
                        HV[swzHV(row, p * 128 + d)] = (f16)(go * tanh_f(cn));
                    }
                }
            // no barrier between cell(p) and GEMM(p+1): writes hit HV cols p*128+d only,
            // next p reads HV cols (p+1)*128.. and HE - disjoint
        }
        __syncthreads();       // HV writes complete before next v2e (or copy-out)
    }

    // ---- write final h_v (fp16) for the projection kernel: [vertex][128] row-major
    for (int i = tid; i < 64 * 48; i += 512) {
        const int row = i / 48, col0 = (i % 48) * 8;
        *(f16x8*)&hvOut[(size_t)(e0 + row) * 384 + col0] = *(const f16x8*)&HV[swzHV(row, col0)];
    }
#undef GEMM_STEP
}

// logits = h_v @ out_w^T + out_b, swapped MFMA operands (A=out_w, B=h_v) -> each lane
// holds 4 consecutive vocab cols for one vertex -> float4 stores (round-7 verified).
// 512 thr / 8 waves / 32 verts per wave / 256 per block / 384 blocks.
// Ow fragments staged per-nt into double-buffered LDS (8 KB each) so 8 waves share one
// L2 read: Ow traffic 3 GB -> 0.8 GB. One barrier per nt.
__global__ __launch_bounds__(512) void proj_kernel(
    const f16* __restrict__ hv,
    const f16* __restrict__ WFh, const f16* __restrict__ WFl,
    const float* __restrict__ out_b, float* __restrict__ out)
{
    __shared__ f16 S[2][4096];   // [buf][term(2)][kk(4)][lane(64)][8]

    const int tid = threadIdx.x, l = tid & 63;
    const int w = tid >> 6;
    const int v0 = blockIdx.x * 256 + w * 32;
    const int lr = l & 15, lk = l >> 4;

    // stage helper indices: term = tid>>8, kk = (tid>>6)&3, lane = tid&63 -> linear tid*8
    const int skk = (tid >> 6) & 3, slane = tid & 63;
    const f16* sbase = (tid >> 8) ? WFl : WFh;

    f16x8 Bv[2][4];
    #pragma unroll
    for (int vt = 0; vt < 2; ++vt)
        #pragma unroll
        for (int kk = 0; kk < 4; ++kk)
            Bv[vt][kk] = *(const f16x8*)(hv + (v0 + vt * 16 + lr) * D_ + kk * 32 + lk * 8);

    // prologue: stage nt=0 into buf 0
    *(f16x8*)&S[0][tid * 8] = *(const f16x8*)(sbase + ((0 * 4 + skk) * 64 + slane) * 8);

    #pragma unroll 1
    for (int nt = 0; nt < 125; ++nt) {
        __syncthreads();  // buf[nt&1] staged; prior reads of buf[(nt+1)&1] finished
        if (nt + 1 < 125)
            *(f16x8*)&S[(nt + 1) & 1][tid * 8] =
                *(const f16x8*)(sbase + (((nt + 1) * 4 + skk) * 64 + slane) * 8);

        const f16* B = &S[nt & 1][0];
        f32x4 a0 = (f32x4)0.0f, a1 = (f32x4)0.0f;
        #pragma unroll
        for (int kk = 0; kk < 4; ++kk) {
            const f16x8 Ah = *(const f16x8*)(B + (kk * 64 + l) * 8);
            a0 = MFh(Ah, Bv[0][kk], a0);
            a1 = MFh(Ah, Bv[1][kk], a1);
        }
        #pragma unroll
        for (int kk = 0; kk < 4; ++kk) {
            const f16x8 Al = *(const f16x8*)(B + ((4 + kk) * 64 + l) * 8);
            a0 = MFh(Al, Bv[0][kk], a0);
            a1 = MFh(Al, Bv[1][kk], a1);
        }
        const int n0 = nt * 16 + lk * 4;
        const float4 bb = *(const float4*)&out_b[n0];
        {
            const size_t v = (size_t)(v0 + lr);
            float4 o = make_float4(a0[0] + bb.x, a0[1] + bb.y, a0[2] + bb.z, a0[3] + bb.w);
            *(float4*)&out[v * VOCAB_ + n0] = o;
        }
        {
            const size_t v = (size_t)(v0 + 16 + lr);
            float4 o = make_float4(a1[0] + bb.x, a1[1] + bb.y, a1[2] + bb.z, a1[3] + bb.w);
            *(float4*)&out[v * VOCAB_ + n0] = o;
        }
    }
}

extern "C" void kernel_launch(void* const* d_in, const int* in_sizes, int n_in,
                              void* d_out, int out_size, void* d_ws, size_t ws_size,
                              hipStream_t stream)
{
    const int*   x_v     = (const int*)  d_in[0];
    const void*  mask    = d_in[1];
    const float* emb     = (const float*)d_in[2];
    const float* eiw     = (const float*)d_in[3];
    const float* eib     = (const float*)d_in[4];
    const float* Wih_v2e = (const float*)d_in[5];
    const float* Whh_v2e = (const float*)d_in[6];
    const float* bih_v2e = (const float*)d_in[7];
    const float* bhh_v2e = (const float*)d_in[8];
    const float* Wih_e2v = (const float*)d_in[9];
    const float* Whh_e2v = (const float*)d_in[10];
    const float* bih_e2v = (const float*)d_in[11];
    const float* bhh_e2v = (const float*)d_in[12];
    const float* out_w   = (const float*)d_in[13];
    const float* out_b   = (const float*)d_in[14];
    float* out = (float*)d_out;

    // d_ws carve (~74.3 MB; ws_size >= 137 MB per round 1)
    char* ws = (char*)d_ws;
    f16*   hv   = (f16*)(ws);                  // 25165824 B
    f16*   WvF  = (f16*)(ws + 25165824);       // 524288
    f16*   WeF  = (f16*)(ws + 25690112);       // 786432
    f16*   OwFh = (f16*)(ws + 26476544);       // 512000
    f16*   OwFl = (f16*)(ws + 26988544);       // 512000
    float* bv   = (float*)(ws + 27500544);     // 2048
    float* be   = (float*)(ws + 27502592);     // 6144
    int*   flag = (int*)(ws + 27508736);       // 4
    float* cvG  = (float*)(ws + 27525120);     // 50331648  [E][3][128]

    hipMemsetAsync(flag, 0, 4, stream);
    detect_mask_kernel<<<16, 256, 0, stream>>>((const unsigned int*)mask, flag);
    prep_kernel<<<3568, 256, 0, stream>>>(Wih_v2e, Whh_v2e, bih_v2e, bhh_v2e,
                                          Wih_e2v, Whh_e2v, bih_e2v, bhh_e2v, out_w,
                                          WvF, WeF, OwFh, OwFl, bv, be);
    fused_kernel<<<E_CNT / 64, 512, 0, stream>>>(x_v, emb, eiw, eib,
                                                 WvF, WeF, bv, be,
                                                 mask, flag, cvG, hv);
    proj_kernel<<<V_CNT / 256, 512, 0, stream>>>(hv, OwFh, OwFl, out_b, out);
}

// Round 9
// 868.161 us; speedup vs baseline: 1.8349x; 1.1669x over previous
//
#include <hip/hip_runtime.h>

#define E_CNT 32768
#define V_CNT 98304
#define D_ 128
#define VOCAB_ 2000
#define ITERS_ 6

// padded LDS strides (halfs): +24 halfs = +48 B per row.
// row step = 816 B (HV) / 304 B (HE) == 12 banks mod 32 -> 16-row b128 span is 2-way max (free).
#define HV_STRIDE 408
#define HE_STRIDE 152

typedef unsigned short u16;
typedef _Float16 f16;
typedef __attribute__((ext_vector_type(8))) _Float16 f16x8;
typedef __attribute__((ext_vector_type(4))) float f32x4;

__device__ __forceinline__ f32x4 MFh(f16x8 a, f16x8 b, f32x4 c) {
    return __builtin_amdgcn_mfma_f32_16x16x32_f16(a, b, c, 0, 0, 0);
}
// fast sigmoid/tanh: v_exp + v_rcp, no precise-divide expansion
__device__ __forceinline__ float sigmoid_f(float x) {
    return __builtin_amdgcn_rcpf(1.0f + __expf(-x));
}
__device__ __forceinline__ float tanh_f(float x) {
    float ax = fabsf(x);
    float t = fmaf(-2.0f, __builtin_amdgcn_rcpf(__expf(2.0f * ax) + 1.0f), 1.0f);
    return copysignf(t, x);
}

// affine LDS indices (half units) - fully loop-invariant lane base + const offsets
__device__ __forceinline__ int hvI(int row, int col) { return row * HV_STRIDE + col; }
__device__ __forceinline__ int heI(int row, int col) { return row * HE_STRIDE + col; }

__global__ void detect_mask_kernel(const unsigned int* __restrict__ m, int* __restrict__ flag) {
    int i = blockIdx.x * 256 + threadIdx.x;
    if (i < 4096 && m[i] > 1u) atomicOr(flag, 1);
}

// Pack weights into MFMA B-fragment order.
// WvF (fp16): [nt(32)][kk(16)][lane(64)][8]  j = nt*16+(l&15), k = kk*32+(l>>4)*8+r
// WeF (fp16): [p(3)][nt(32)][kk(8)][64][8]
// OwF (fp16 hi/lo): [nt(125)][kk(4)][64][8]
__global__ void prep_kernel(
    const float* __restrict__ Wih_v2e, const float* __restrict__ Whh_v2e,
    const float* __restrict__ bih_v2e, const float* __restrict__ bhh_v2e,
    const float* __restrict__ Wih_e2v, const float* __restrict__ Whh_e2v,
    const float* __restrict__ bih_e2v, const float* __restrict__ bhh_e2v,
    const float* __restrict__ out_w,
    f16* __restrict__ WvF, f16* __restrict__ WeF,
    f16* __restrict__ OwFh, f16* __restrict__ OwFl,
    float* __restrict__ bv, float* __restrict__ be)
{
    int idx = blockIdx.x * 256 + threadIdx.x;
    if (idx < 262144) {
        const int r = idx & 7, l = (idx >> 3) & 63, t = idx >> 9;
        const int kk = t & 15, nt = t >> 4;
        const int j = nt * 16 + (l & 15);
        const int k = kk * 32 + (l >> 4) * 8 + r;
        const float w = (k < 384) ? Wih_v2e[j * 384 + k] : Whh_v2e[j * 128 + (k - 384)];
        WvF[idx] = (f16)w;
        return;
    }
    idx -= 262144;
    if (idx < 393216) {
        const int r = idx & 7, l = (idx >> 3) & 63, t = idx >> 9;  // t < 768
        const int kk = t & 7, nt = (t >> 3) & 31, p = t >> 8;
        const int j = nt * 16 + (l & 15);
        const int k = kk * 32 + (l >> 4) * 8 + r;
        const float w = (k < 128) ? Wih_e2v[(p * 512 + j) * 128 + k]
                                  : Whh_e2v[(p * 512 + j) * 128 + (k - 128)];
        WeF[idx] = (f16)w;
        return;
    }
    idx -= 393216;
    if (idx < 256000) {
        const int r = idx & 7, l = (idx >> 3) & 63, t = idx >> 9;  // t < 500
        const int kk = t & 3, nt = t >> 2;
        const int j = nt * 16 + (l & 15);
        const int k = kk * 32 + (l >> 4) * 8 + r;
        const float w = out_w[j * 128 + k];
        const f16 h = (f16)w;
        OwFh[idx] = h;
        OwFl[idx] = (f16)(w - (float)h);
        return;
    }
    idx -= 256000;
    if (idx < 512) { bv[idx] = bih_v2e[idx] + bhh_v2e[idx]; return; }
    idx -= 512;
    if (idx < 1536) { be[idx] = bih_e2v[idx] + bhh_e2v[idx]; return; }
}

// Persistent fused kernel: block = 512 threads (8 waves) owns 64 edges for all 6 iters.
// Wave c = wid (0..7): gate-dim slice d = c*16+lr for all 4 gates, edge tiles mt=0..3.
// Static LDS 71.7 KB -> 2 blocks/CU -> VGPR budget 128 (round-8 verified: no spills).
// PADDED (not XOR) layout: every ds_read is lane_base + compile-time const ->
// addressing VALU ~0, offsets folded into ds_read offset:imm (round-8 bottleneck:
// VALUBusy 50% on per-kk XOR-swizzle address recompute).
// c_v in global f32 [E][3][128] (L3-resident); it==0 skips the load (no init pass).
__global__ __launch_bounds__(512)
void fused_kernel(
    const int* __restrict__ x_v,
    const float* __restrict__ emb,
    const float* __restrict__ eiw, const float* __restrict__ eib,
    const f16* __restrict__ WvF, const f16* __restrict__ WeF,
    const float* __restrict__ bv, const float* __restrict__ be,
    const void* __restrict__ mask, const int* __restrict__ flagp,
    float* __restrict__ cvG,
    f16* __restrict__ hvOut)
{
    __shared__ f16 HV[64 * HV_STRIDE];   // 52224 B
    __shared__ f16 HE[64 * HE_STRIDE];   // 19456 B -> 71680 B total

    const int tid = threadIdx.x;
    const int c = tid >> 6, l = tid & 63;
    const int lr = l & 15, lk = l >> 4;
    const int e0 = blockIdx.x * 64;

    // ---- init h_v from embeddings (fp16 into LDS)
    for (int i = tid; i < 64 * 48; i += 512) {
        const int row = i / 48, seg = i % 48;
        const int col0 = seg * 8;
        int id = x_v[(e0 + row) * 3 + (col0 >> 7)];
        if (id < 0 || id > VOCAB_) id = VOCAB_;
        const float* s = emb + id * D_ + (col0 & 127);
        float4 a = *(const float4*)s, b = *(const float4*)(s + 4);
        f16x8 H;
        H[0] = (f16)a.x; H[1] = (f16)a.y; H[2] = (f16)a.z; H[3] = (f16)a.w;
        H[4] = (f16)b.x; H[5] = (f16)b.y; H[6] = (f16)b.z; H[7] = (f16)b.w;
        *(f16x8*)&HV[hvI(row, col0)] = H;
    }
    // ---- init h_e (same vector for every edge)
    for (int i = tid; i < 64 * 16; i += 512) {
        const int row = i / 16, col0 = (i % 16) * 8;
        f16x8 H;
        #pragma unroll
        for (int j = 0; j < 8; ++j) H[j] = (f16)(eiw[col0 + j] + eib[col0 + j]);
        *(f16x8*)&HE[heI(row, col0)] = H;
    }

    // ---- per-lane constants: mask bits, c_e register state
    const int isByte = *flagp;
    unsigned mbits[3];
    #pragma unroll
    for (int p = 0; p < 3; ++p) {
        unsigned mb = 0;
        #pragma unroll
        for (int mt = 0; mt < 4; ++mt)
            #pragma unroll
            for (int r = 0; r < 4; ++r) {
                const int v = (e0 + mt * 16 + lk * 4 + r) * 3 + p;
                const bool m = isByte ? (((const unsigned char*)mask)[v] != 0)
                                      : (((const int*)mask)[v] != 0);
                mb |= (unsigned)m << (mt * 4 + r);
            }
        mbits[p] = mb;
    }
    const int d = c * 16 + lr;
    float ce[4][4];
    #pragma unroll
    for (int mt = 0; mt < 4; ++mt)
        #pragma unroll
        for (int r = 0; r < 4; ++r) ce[mt][r] = 0.0f;

    __syncthreads();

// g outer, mt inner: same-accumulator MFMA distance 4
#define GEMM_STEP(WF, FBASE)                                                  \
    { _Pragma("unroll")                                                       \
      for (int g = 0; g < 4; ++g) {                                           \
          f16x8 B = *(const f16x8*)((WF) + (FBASE));                          \
          _Pragma("unroll")                                                   \
          for (int mt = 0; mt < 4; ++mt) acc[mt][g] = MFh(Ah[mt], B, acc[mt][g]); \
      } }

    // loop-invariant lane read bases (half units)
    const int rdHV = lr * HV_STRIDE + lk * 8;
    const int rdHE = lr * HE_STRIDE + lk * 8;

    #pragma unroll 1
    for (int it = 0; it < ITERS_; ++it) {
        // ======== vertex -> edge ========
        {
            f32x4 acc[4][4];
            #pragma unroll
            for (int mt = 0; mt < 4; ++mt)
                #pragma unroll
                for (int g = 0; g < 4; ++g) acc[mt][g] = (f32x4)0.0f;

            #pragma unroll 1
            for (int kk = 0; kk < 12; ++kk) {
                f16x8 Ah[4];
                #pragma unroll
                for (int mt = 0; mt < 4; ++mt)
                    Ah[mt] = *(const f16x8*)&HV[rdHV + mt * 16 * HV_STRIDE + kk * 32];
                GEMM_STEP(WvF, (((g * 8 + c) * 16 + kk) * 64 + l) * 8)
            }
            #pragma unroll 1
            for (int kk = 12; kk < 16; ++kk) {
                f16x8 Ah[4];
                #pragma unroll
                for (int mt = 0; mt < 4; ++mt)
                    Ah[mt] = *(const f16x8*)&HE[rdHE + mt * 16 * HE_STRIDE + (kk - 12) * 32];
                GEMM_STEP(WvF, (((g * 8 + c) * 16 + kk) * 64 + l) * 8)
            }
            __syncthreads();   // all HE reads done before HE writes
            const float bvi = bv[d], bvf = bv[128 + d], bvg = bv[256 + d], bvo = bv[384 + d];
            #pragma unroll
            for (int mt = 0; mt < 4; ++mt)
                #pragma unroll
                for (int r = 0; r < 4; ++r) {
                    const int row = mt * 16 + lk * 4 + r;
                    float gi = sigmoid_f(acc[mt][0][r] + bvi);
                    float gf = sigmoid_f(acc[mt][1][r] + bvf);
                    float gg = tanh_f(acc[mt][2][r] + bvg);
                    float go = sigmoid_f(acc[mt][3][r] + bvo);
                    float cn = gf * ce[mt][r] + gi * gg;
                    ce[mt][r] = cn;
                    HE[heI(row, d)] = (f16)(go * tanh_f(cn));
                }
            __syncthreads();   // HE complete before e2v reads
        }
        // ======== edge -> vertex (3 position-specific LSTMs) ========
        #pragma unroll 1
        for (int p = 0; p < 3; ++p) {
            f32x4 acc[4][4];
            #pragma unroll
            for (int mt = 0; mt < 4; ++mt)
                #pragma unroll
                for (int g = 0; g < 4; ++g) acc[mt][g] = (f32x4)0.0f;

            #pragma unroll 1
            for (int kk = 0; kk < 4; ++kk) {
                f16x8 Ah[4];
                #pragma unroll
                for (int mt = 0; mt < 4; ++mt)
                    Ah[mt] = *(const f16x8*)&HE[rdHE + mt * 16 * HE_STRIDE + kk * 32];
                GEMM_STEP(WeF, ((((p * 32) + (g * 8 + c)) * 8 + kk) * 64 + l) * 8)
            }
            #pragma unroll 1
            for (int kk = 4; kk < 8; ++kk) {
                f16x8 Ah[4];
                #pragma unroll
                for (int mt = 0; mt < 4; ++mt)
                    Ah[mt] = *(const f16x8*)&HV[rdHV + mt * 16 * HV_STRIDE + p * 128 + (kk - 4) * 32];
                GEMM_STEP(WeF, ((((p * 32) + (g * 8 + c)) * 8 + kk) * 64 + l) * 8)
            }
            __syncthreads();   // all HV[p]/HE reads done before HV[p] writes
            const float bei = be[p * 512 + d], bef = be[p * 512 + 128 + d];
            const float beg = be[p * 512 + 256 + d], beo = be[p * 512 + 384 + d];
            #pragma unroll
            for (int mt = 0; mt < 4; ++mt)
                #pragma unroll
                for (int r = 0; r < 4; ++r) {
                    if ((mbits[p] >> (mt * 4 + r)) & 1u) {
                        const int row = mt * 16 + lk * 4 + r;
                        float gi = sigmoid_f(acc[mt][0][r] + bei);
                        float gf = sigmoid_f(acc[mt][1][r] + bef);
                        float gg = tanh_f(acc[mt][2][r] + beg);
                        float go = sigmoid_f(acc[mt][3][r] + beo);
                        const size_t co = ((size_t)(e0 + row) * 3 + p) * 128 + d;
                        float cvold = (it == 0) ? 0.0f : cvG[co];
                        float cn = gf * cvold + gi * gg;
                        cvG[co] = cn;
                        HV[hvI(row, p * 128 + d)] = (f16)(go * tanh_f(cn));
                    }
                }
            // no barrier between cell(p) and GEMM(p+1): writes hit HV cols p*128+d only,
            // next p reads HV cols (p+1)*128.. and HE - disjoint
        }
        __syncthreads();       // HV writes complete before next v2e (or copy-out)
    }

    // ---- write final h_v (fp16) for the projection kernel: [vertex][128] row-major
    for (int i = tid; i < 64 * 48; i += 512) {
        const int row = i / 48, col0 = (i % 48) * 8;
        *(f16x8*)&hvOut[(size_t)(e0 + row) * 384 + col0] = *(const f16x8*)&HV[hvI(row, col0)];
    }
#undef GEMM_STEP
}

// logits = h_v @ out_w^T + out_b, swapped MFMA operands (A=out_w, B=h_v) -> each lane
// holds 4 consecutive vocab cols for one vertex -> float4 stores.
// 512 thr / 8 waves / 32 verts per wave / 256 per block / 384 blocks.
// Ow fragments staged per-nt into double-buffered LDS (8 KB each); 1 barrier per nt.
__global__ __launch_bounds__(512) void proj_kernel(
    const f16* __restrict__ hv,
    const f16* __restrict__ WFh, const f16* __restrict__ WFl,
    const float* __restrict__ out_b, float* __restrict__ out)
{
    __shared__ f16 S[2][4096];   // [buf][term(2)][kk(4)][lane(64)][8]

    const int tid = threadIdx.x, l = tid & 63;
    const int w = tid >> 6;
    const int v0 = blockIdx.x * 256 + w * 32;
    const int lr = l & 15, lk = l >> 4;

    // stage helper indices: term = tid>>8, kk = (tid>>6)&3, lane = tid&63 -> linear tid*8
    const int skk = (tid >> 6) & 3, slane = tid & 63;
    const f16* sbase = (tid >> 8) ? WFl : WFh;

    f16x8 Bv[2][4];
    #pragma unroll
    for (int vt = 0; vt < 2; ++vt)
        #pragma unroll
        for (int kk = 0; kk < 4; ++kk)
            Bv[vt][kk] = *(const f16x8*)(hv + (v0 + vt * 16 + lr) * D_ + kk * 32 + lk * 8);

    // prologue: stage nt=0 into buf 0
    *(f16x8*)&S[0][tid * 8] = *(const f16x8*)(sbase + ((0 * 4 + skk) * 64 + slane) * 8);

    #pragma unroll 1
    for (int nt = 0; nt < 125; ++nt) {
        __syncthreads();  // buf[nt&1] staged; prior reads of buf[(nt+1)&1] finished
        if (nt + 1 < 125)
            *(f16x8*)&S[(nt + 1) & 1][tid * 8] =
                *(const f16x8*)(sbase + (((nt + 1) * 4 + skk) * 64 + slane) * 8);

        const f16* B = &S[nt & 1][0];
        f32x4 a0 = (f32x4)0.0f, a1 = (f32x4)0.0f;
        #pragma unroll
        for (int kk = 0; kk < 4; ++kk) {
            const f16x8 Ah = *(const f16x8*)(B + (kk * 64 + l) * 8);
            a0 = MFh(Ah, Bv[0][kk], a0);
            a1 = MFh(Ah, Bv[1][kk], a1);
        }
        #pragma unroll
        for (int kk = 0; kk < 4; ++kk) {
            const f16x8 Al = *(const f16x8*)(B + ((4 + kk) * 64 + l) * 8);
            a0 = MFh(Al, Bv[0][kk], a0);
            a1 = MFh(Al, Bv[1][kk], a1);
        }
        const int n0 = nt * 16 + lk * 4;
        const float4 bb = *(const float4*)&out_b[n0];
        {
            const size_t v = (size_t)(v0 + lr);
            float4 o = make_float4(a0[0] + bb.x, a0[1] + bb.y, a0[2] + bb.z, a0[3] + bb.w);
            *(float4*)&out[v * VOCAB_ + n0] = o;
        }
        {
            const size_t v = (size_t)(v0 + 16 + lr);
            float4 o = make_float4(a1[0] + bb.x, a1[1] + bb.y, a1[2] + bb.z, a1[3] + bb.w);
            *(float4*)&out[v * VOCAB_ + n0] = o;
        }
    }
}

extern "C" void kernel_launch(void* const* d_in, const int* in_sizes, int n_in,
                              void* d_out, int out_size, void* d_ws, size_t ws_size,
                              hipStream_t stream)
{
    const int*   x_v     = (const int*)  d_in[0];
    const void*  mask    = d_in[1];
    const float* emb     = (const float*)d_in[2];
    const float* eiw     = (const float*)d_in[3];
    const float* eib     = (const float*)d_in[4];
    const float* Wih_v2e = (const float*)d_in[5];
    const float* Whh_v2e = (const float*)d_in[6];
    const float* bih_v2e = (const float*)d_in[7];
    const float* bhh_v2e = (const float*)d_in[8];
    const float* Wih_e2v = (const float*)d_in[9];
    const float* Whh_e2v = (const float*)d_in[10];
    const float* bih_e2v = (const float*)d_in[11];
    const float* bhh_e2v = (const float*)d_in[12];
    const float* out_w   = (const float*)d_in[13];
    const float* out_b   = (const float*)d_in[14];
    float* out = (float*)d_out;

    // d_ws carve (~74.3 MB)
    char* ws = (char*)d_ws;
    f16*   hv   = (f16*)(ws);                  // 25165824 B
    f16*   WvF  = (f16*)(ws + 25165824);       // 524288
    f16*   WeF  = (f16*)(ws + 25690112);       // 786432
    f16*   OwFh = (f16*)(ws + 26476544);       // 512000
    f16*   OwFl = (f16*)(ws + 26988544);       // 512000
    float* bv   = (float*)(ws + 27500544);     // 2048
    float* be   = (float*)(ws + 27502592);     // 6144
    int*   flag = (int*)(ws + 27508736);       // 4
    float* cvG  = (float*)(ws + 27525120);     // 50331648  [E][3][128]

    hipMemsetAsync(flag, 0, 4, stream);
    detect_mask_kernel<<<16, 256, 0, stream>>>((const unsigned int*)mask, flag);
    prep_kernel<<<3568, 256, 0, stream>>>(Wih_v2e, Whh_v2e, bih_v2e, bhh_v2e,
                                          Wih_e2v, Whh_e2v, bih_e2v, bhh_e2v, out_w,
                                          WvF, WeF, OwFh, OwFl, bv, be);
    fused_kernel<<<E_CNT / 64, 512, 0, stream>>>(x_v, emb, eiw, eib,
                                                 WvF, WeF, bv, be,
                                                 mask, flag, cvG, hv);
    proj_kernel<<<V_CNT / 256, 512, 0, stream>>>(hv, OwFh, OwFl, out_b, out);
}